// Round 6
// baseline (277.551 us; speedup 1.0000x reference)
//
#include <hip/hip_runtime.h>

#define NNODES 50000
#define NEDGES 640000
#define DIM 128
#define SCAN_BLK 49   // ceil(50000 / 1024)

// ---------------- CSR build ----------------

__global__ void zero_k(int* __restrict__ p, int n) {
    int i = blockIdx.x * blockDim.x + threadIdx.x;
    if (i < n) p[i] = 0;
}

__global__ void hist_k(const int* __restrict__ ei, int* __restrict__ deg, int E) {
    int e = blockIdx.x * blockDim.x + threadIdx.x;
    if (e < E) atomicAdd(&deg[ei[E + e]], 1);
}

__global__ void scanA_k(const int* __restrict__ deg, int* __restrict__ bsum) {
    const int t = threadIdx.x, b = blockIdx.x;
    const int base = b * 1024 + t * 4;
    int4 v = make_int4(0, 0, 0, 0);
    if (base < NNODES) v = *(const int4*)&deg[base];
    int s = v.x + v.y + v.z + v.w;
    #pragma unroll
    for (int d = 32; d > 0; d >>= 1) s += __shfl_down(s, d, 64);
    __shared__ int ws[4];
    if ((t & 63) == 0) ws[t >> 6] = s;
    __syncthreads();
    if (t == 0) bsum[b] = ws[0] + ws[1] + ws[2] + ws[3];
}

__global__ void scanB_k(const int* __restrict__ bsum, int* __restrict__ bbase) {
    const int t = threadIdx.x;
    int orig = (t < SCAN_BLK) ? bsum[t] : 0;
    int v = orig;
    #pragma unroll
    for (int d = 1; d < 64; d <<= 1) {
        int u = __shfl_up(v, d, 64);
        if (t >= d) v += u;
    }
    if (t < SCAN_BLK) bbase[t] = v - orig;
}

__global__ void scanC_k(const int* __restrict__ deg, const int* __restrict__ bbase,
                        int* __restrict__ off, int* __restrict__ cur) {
    __shared__ int ws[4];
    const int t = threadIdx.x, b = blockIdx.x;
    const int base = b * 1024 + t * 4;
    int4 v = make_int4(0, 0, 0, 0);
    if (base < NNODES) v = *(const int4*)&deg[base];
    const int s = v.x + v.y + v.z + v.w;
    const int lane = t & 63, w = t >> 6;
    int sv = s;
    #pragma unroll
    for (int d = 1; d < 64; d <<= 1) {
        int u = __shfl_up(sv, d, 64);
        if (lane >= d) sv += u;
    }
    if (lane == 63) ws[w] = sv;
    __syncthreads();
    int wbase = 0;
    #pragma unroll
    for (int i = 0; i < 4; ++i) if (i < w) wbase += ws[i];
    int ex = bbase[b] + wbase + (sv - s);
    if (base < NNODES) {
        int4 o;
        o.x = ex;
        o.y = o.x + v.x;
        o.z = o.y + v.y;
        o.w = o.z + v.z;
        *(int4*)&off[base] = o;
        *(int4*)&cur[base] = o;
    }
    if (b == 0 && t == 0) off[NNODES] = NEDGES;
}

__global__ void fill_k(const int* __restrict__ ei, int* __restrict__ cur,
                       int* __restrict__ srclist, int E) {
    int e = blockIdx.x * blockDim.x + threadIdx.x;
    if (e >= E) return;
    int src = ei[e];
    int dst = ei[E + e];
    int pos = atomicAdd(&cur[dst], 1);
    srclist[pos] = src;
}

// ---------------- bf16 conversion of x ----------------
__device__ __forceinline__ unsigned int bf16rne(float f) {
    unsigned int u = __float_as_uint(f);
    return (u + 0x7FFFu + ((u >> 16) & 1u)) >> 16;   // RNE to bf16 (no NaN inputs)
}

// each thread packs 8 floats -> one uint4
__global__ void cvt_k(const float4* __restrict__ x4, uint4* __restrict__ xb4, int n8) {
    int i = blockIdx.x * blockDim.x + threadIdx.x;
    if (i >= n8) return;
    float4 a = x4[2 * i], b = x4[2 * i + 1];
    uint4 o;
    o.x = bf16rne(a.x) | (bf16rne(a.y) << 16);
    o.y = bf16rne(a.z) | (bf16rne(a.w) << 16);
    o.z = bf16rne(b.x) | (bf16rne(b.y) << 16);
    o.w = bf16rne(b.z) | (bf16rne(b.w) << 16);
    xb4[i] = o;
}

// ---------------- gather aggregation, bf16 neighbor reads ----------------
// 16 lanes per node, each lane owns components lane*8..lane*8+7.
// Self term read exact f32; neighbor rows read as packed bf16 (256B/row).
__device__ __forceinline__ float bflo(unsigned int p) { return __uint_as_float(p << 16); }
__device__ __forceinline__ float bfhi(unsigned int p) { return __uint_as_float(p & 0xFFFF0000u); }

__global__ void gather_bf_k(const float4* __restrict__ x4, const uint4* __restrict__ xb4,
                            const int* __restrict__ off, const int* __restrict__ srclist,
                            float4* __restrict__ hp4) {
    int t = blockIdx.x * blockDim.x + threadIdx.x;
    int node = t >> 4;
    if (node >= NNODES) return;
    int lane = t & 15;
    float4 a0 = x4[(size_t)node * 32 + lane * 2];
    float4 a1 = x4[(size_t)node * 32 + lane * 2 + 1];
    int beg = off[node], end = off[node + 1];
    for (int j = beg; j < end; ++j) {
        int s = srclist[j];
        uint4 p = xb4[(size_t)s * 16 + lane];
        a0.x += bflo(p.x); a0.y += bfhi(p.x);
        a0.z += bflo(p.y); a0.w += bfhi(p.y);
        a1.x += bflo(p.z); a1.y += bfhi(p.z);
        a1.z += bflo(p.w); a1.w += bfhi(p.w);
    }
    hp4[(size_t)node * 32 + lane * 2]     = a0;
    hp4[(size_t)node * 32 + lane * 2 + 1] = a1;
}

// f32 gather (fallback when ws can't hold xb)
__global__ void gather_k(const float4* __restrict__ x4, const int* __restrict__ off,
                         const int* __restrict__ srclist, float4* __restrict__ hp4) {
    int t = blockIdx.x * blockDim.x + threadIdx.x;
    int node = t >> 5;
    if (node >= NNODES) return;
    int lane = t & 31;
    float4 acc = x4[(size_t)node * 32 + lane];
    int beg = off[node], end = off[node + 1];
    for (int j = beg; j < end; ++j) {
        int s = srclist[j];
        float4 v = x4[(size_t)s * 32 + lane];
        acc.x += v.x; acc.y += v.y; acc.z += v.z; acc.w += v.w;
    }
    hp4[(size_t)node * 32 + lane] = acc;
}

// ---------------- fallback atomic scatter (if ws too small for CSR) ----------------
__global__ void copy_k(const float4* __restrict__ src, float4* __restrict__ dst, int n4) {
    int i = blockIdx.x * blockDim.x + threadIdx.x;
    if (i < n4) dst[i] = src[i];
}

__global__ void scatter_k(const float4* __restrict__ x4, const int* __restrict__ ei,
                          float* __restrict__ hp, int E) {
    int t = blockIdx.x * blockDim.x + threadIdx.x;
    int e = t >> 5;
    if (e >= E) return;
    int lane = t & 31;
    int src = ei[e];
    int dst = ei[E + e];
    float4 v = x4[(size_t)src * 32 + lane];
    float* p = hp + (size_t)dst * DIM + lane * 4;
    unsafeAtomicAdd(p + 0, v.x);
    unsafeAtomicAdd(p + 1, v.y);
    unsafeAtomicAdd(p + 2, v.z);
    unsafeAtomicAdd(p + 3, v.w);
}

// ---------------- fused MLP — 8 rows x 4 cols per thread ----------------
// 128 threads/block, 32 rows/block. LDS: W 64KB + As 16KB = 80KB -> 2 blocks/CU.
// Per 4-k iter per thread: 128 FMA vs 4 full-width w-reads -> VALU-bound, not LDS.
__launch_bounds__(128)
__global__ void mlp_k(float* __restrict__ io,
                      const float* __restrict__ W1, const float* __restrict__ b1,
                      const float* __restrict__ W2, const float* __restrict__ b2,
                      int N) {
    __shared__ float Wl[DIM * DIM];   // 64 KB
    __shared__ float As[32][DIM];     // 16 KB

    const int tid = threadIdx.x;      // 0..127
    const int r0 = blockIdx.x * 32;
    const int tc = tid & 31;          // cols tc*4..tc*4+3
    const int tr = tid >> 5;          // 0..3 -> rows tr*8..tr*8+7

    // stage W1 (contiguous float4, conflict-free)
    {
        const float4* w4 = (const float4*)W1;
        float4* wl4 = (float4*)Wl;
        #pragma unroll
        for (int i = 0; i < 32; ++i) wl4[tid + i * 128] = w4[tid + i * 128];
    }
    // stage A row-major (contiguous copy)
    {
        const float4* io4 = (const float4*)io;
        float4* as4 = (float4*)As;
        #pragma unroll
        for (int i = 0; i < 8; ++i) {
            int p = tid + i * 128;       // [0,1024): row=p>>5, k4=p&31
            int row = p >> 5;
            float4 v = make_float4(0.f, 0.f, 0.f, 0.f);
            if (r0 + row < N) v = io4[(size_t)(r0 + row) * 32 + (p & 31)];
            as4[p] = v;
        }
    }
    __syncthreads();

    // ---- layer 1 ----
    float acc[8][4];
    #pragma unroll
    for (int i = 0; i < 8; ++i)
        #pragma unroll
        for (int j = 0; j < 4; ++j) acc[i][j] = 0.f;

    for (int kc = 0; kc < 32; ++kc) {
        float4 a[8], w[4];
        #pragma unroll
        for (int i = 0; i < 8; ++i) a[i] = *(const float4*)&As[tr * 8 + i][kc * 4];
        #pragma unroll
        for (int kk = 0; kk < 4; ++kk) w[kk] = *(const float4*)&Wl[(kc * 4 + kk) * DIM + tc * 4];
        float af[8][4];
        #pragma unroll
        for (int i = 0; i < 8; ++i) {
            af[i][0] = a[i].x; af[i][1] = a[i].y; af[i][2] = a[i].z; af[i][3] = a[i].w;
        }
        #pragma unroll
        for (int kk = 0; kk < 4; ++kk) {
            float wv[4] = {w[kk].x, w[kk].y, w[kk].z, w[kk].w};
            #pragma unroll
            for (int i = 0; i < 8; ++i)
                #pragma unroll
                for (int j = 0; j < 4; ++j)
                    acc[i][j] = fmaf(af[i][kk], wv[j], acc[i][j]);
        }
    }

    float4 bv1 = ((const float4*)b1)[tc];
    float h[8][4];
    #pragma unroll
    for (int i = 0; i < 8; ++i) {
        h[i][0] = fmaxf(acc[i][0] + bv1.x, 0.f);
        h[i][1] = fmaxf(acc[i][1] + bv1.y, 0.f);
        h[i][2] = fmaxf(acc[i][2] + bv1.z, 0.f);
        h[i][3] = fmaxf(acc[i][3] + bv1.w, 0.f);
    }

    __syncthreads();

    // stage W2; write h back row-major (lane-contiguous b128)
    {
        const float4* w4 = (const float4*)W2;
        float4* wl4 = (float4*)Wl;
        #pragma unroll
        for (int i = 0; i < 32; ++i) wl4[tid + i * 128] = w4[tid + i * 128];
    }
    #pragma unroll
    for (int i = 0; i < 8; ++i)
        *(float4*)&As[tr * 8 + i][tc * 4] = make_float4(h[i][0], h[i][1], h[i][2], h[i][3]);
    __syncthreads();

    // ---- layer 2 ----
    #pragma unroll
    for (int i = 0; i < 8; ++i)
        #pragma unroll
        for (int j = 0; j < 4; ++j) acc[i][j] = 0.f;

    for (int kc = 0; kc < 32; ++kc) {
        float4 a[8], w[4];
        #pragma unroll
        for (int i = 0; i < 8; ++i) a[i] = *(const float4*)&As[tr * 8 + i][kc * 4];
        #pragma unroll
        for (int kk = 0; kk < 4; ++kk) w[kk] = *(const float4*)&Wl[(kc * 4 + kk) * DIM + tc * 4];
        float af[8][4];
        #pragma unroll
        for (int i = 0; i < 8; ++i) {
            af[i][0] = a[i].x; af[i][1] = a[i].y; af[i][2] = a[i].z; af[i][3] = a[i].w;
        }
        #pragma unroll
        for (int kk = 0; kk < 4; ++kk) {
            float wv[4] = {w[kk].x, w[kk].y, w[kk].z, w[kk].w};
            #pragma unroll
            for (int i = 0; i < 8; ++i)
                #pragma unroll
                for (int j = 0; j < 4; ++j)
                    acc[i][j] = fmaf(af[i][kk], wv[j], acc[i][j]);
        }
    }

    float4 bv2 = ((const float4*)b2)[tc];
    float4* io4 = (float4*)io;
    #pragma unroll
    for (int ri = 0; ri < 8; ++ri) {
        int row = r0 + tr * 8 + ri;
        if (row < N) {
            float4 o = make_float4(acc[ri][0] + bv2.x, acc[ri][1] + bv2.y,
                                   acc[ri][2] + bv2.z, acc[ri][3] + bv2.w);
            io4[(size_t)row * 32 + tc] = o;
        }
    }
}

extern "C" void kernel_launch(void* const* d_in, const int* in_sizes, int n_in,
                              void* d_out, int out_size, void* d_ws, size_t ws_size,
                              hipStream_t stream) {
    const float* x  = (const float*)d_in[0];
    const int*   ei = (const int*)d_in[1];
    const float* W1 = (const float*)d_in[2];
    const float* b1 = (const float*)d_in[3];
    const float* W2 = (const float*)d_in[4];
    const float* b2 = (const float*)d_in[5];
    float* out = (float*)d_out;

    // ws layout: xb[NNODES*DIM bf16 = 12.8MB, 16B-aligned at base] |
    //            deg[NNODES] | cur[NNODES] | off[NNODES+1] | srclist[NEDGES] | bsum[64] | bbase[64]
    const size_t xb_bytes  = (size_t)NNODES * DIM * 2;
    const size_t csr_ints  = (size_t)(NNODES * 2 + (NNODES + 1) + NEDGES + 128);
    const size_t need_csr  = csr_ints * sizeof(int);
    const size_t need_bf   = xb_bytes + need_csr;

    if (ws_size >= need_csr) {
        int* ibase;
        uint4* xb4 = nullptr;
        bool use_bf = (ws_size >= need_bf);
        if (use_bf) {
            xb4 = (uint4*)d_ws;
            ibase = (int*)((char*)d_ws + xb_bytes);
        } else {
            ibase = (int*)d_ws;
        }
        int* deg = ibase;
        int* cur = deg + NNODES;
        int* off = cur + NNODES;
        int* srclist = off + NNODES + 1;
        int* bsum = srclist + NEDGES;
        int* bbase = bsum + 64;

        zero_k<<<(NNODES + 255) / 256, 256, 0, stream>>>(deg, NNODES);
        hist_k<<<(NEDGES + 255) / 256, 256, 0, stream>>>(ei, deg, NEDGES);
        scanA_k<<<SCAN_BLK, 256, 0, stream>>>(deg, bsum);
        scanB_k<<<1, 64, 0, stream>>>(bsum, bbase);
        scanC_k<<<SCAN_BLK, 256, 0, stream>>>(deg, bbase, off, cur);
        fill_k<<<(NEDGES + 255) / 256, 256, 0, stream>>>(ei, cur, srclist, NEDGES);

        if (use_bf) {
            int n8 = NNODES * DIM / 8;
            cvt_k<<<(n8 + 255) / 256, 256, 0, stream>>>((const float4*)x, xb4, n8);
            int gthreads = NNODES * 16;
            gather_bf_k<<<(gthreads + 255) / 256, 256, 0, stream>>>(
                (const float4*)x, xb4, off, srclist, (float4*)out);
        } else {
            int gthreads = NNODES * 32;
            gather_k<<<(gthreads + 255) / 256, 256, 0, stream>>>(
                (const float4*)x, off, srclist, (float4*)out);
        }
    } else {
        int n4 = NNODES * DIM / 4;
        copy_k<<<(n4 + 255) / 256, 256, 0, stream>>>((const float4*)x, (float4*)out, n4);
        int sthreads = NEDGES * 32;
        scatter_k<<<(sthreads + 255) / 256, 256, 0, stream>>>((const float4*)x, ei, out, NEDGES);
    }

    mlp_k<<<(NNODES + 31) / 32, 128, 0, stream>>>(out, W1, b1, W2, b2, NNODES);
}

// Round 7
// 237.425 us; speedup vs baseline: 1.1690x; 1.1690x over previous
//
#include <hip/hip_runtime.h>

#define NNODES 50000
#define NEDGES 640000
#define DIM 128
#define SCAN_BLK 49   // ceil(50000 / 1024)

typedef unsigned short u16;
typedef __attribute__((ext_vector_type(8))) short short8;   // 8 bf16 (4 VGPRs)
typedef __attribute__((ext_vector_type(4))) float f32x4;

// ---------------- CSR build ----------------

__global__ void zero_k(int* __restrict__ p, int n) {
    int i = blockIdx.x * blockDim.x + threadIdx.x;
    if (i < n) p[i] = 0;
}

__global__ void hist_k(const int* __restrict__ ei, int* __restrict__ deg, int E) {
    int e = blockIdx.x * blockDim.x + threadIdx.x;
    if (e < E) atomicAdd(&deg[ei[E + e]], 1);
}

__global__ void scanA_k(const int* __restrict__ deg, int* __restrict__ bsum) {
    const int t = threadIdx.x, b = blockIdx.x;
    const int base = b * 1024 + t * 4;
    int4 v = make_int4(0, 0, 0, 0);
    if (base < NNODES) v = *(const int4*)&deg[base];
    int s = v.x + v.y + v.z + v.w;
    #pragma unroll
    for (int d = 32; d > 0; d >>= 1) s += __shfl_down(s, d, 64);
    __shared__ int ws[4];
    if ((t & 63) == 0) ws[t >> 6] = s;
    __syncthreads();
    if (t == 0) bsum[b] = ws[0] + ws[1] + ws[2] + ws[3];
}

__global__ void scanB_k(const int* __restrict__ bsum, int* __restrict__ bbase) {
    const int t = threadIdx.x;
    int orig = (t < SCAN_BLK) ? bsum[t] : 0;
    int v = orig;
    #pragma unroll
    for (int d = 1; d < 64; d <<= 1) {
        int u = __shfl_up(v, d, 64);
        if (t >= d) v += u;
    }
    if (t < SCAN_BLK) bbase[t] = v - orig;
}

__global__ void scanC_k(const int* __restrict__ deg, const int* __restrict__ bbase,
                        int* __restrict__ off, int* __restrict__ cur) {
    __shared__ int ws[4];
    const int t = threadIdx.x, b = blockIdx.x;
    const int base = b * 1024 + t * 4;
    int4 v = make_int4(0, 0, 0, 0);
    if (base < NNODES) v = *(const int4*)&deg[base];
    const int s = v.x + v.y + v.z + v.w;
    const int lane = t & 63, w = t >> 6;
    int sv = s;
    #pragma unroll
    for (int d = 1; d < 64; d <<= 1) {
        int u = __shfl_up(sv, d, 64);
        if (lane >= d) sv += u;
    }
    if (lane == 63) ws[w] = sv;
    __syncthreads();
    int wbase = 0;
    #pragma unroll
    for (int i = 0; i < 4; ++i) if (i < w) wbase += ws[i];
    int ex = bbase[b] + wbase + (sv - s);
    if (base < NNODES) {
        int4 o;
        o.x = ex;
        o.y = o.x + v.x;
        o.z = o.y + v.y;
        o.w = o.z + v.z;
        *(int4*)&off[base] = o;
        *(int4*)&cur[base] = o;
    }
    if (b == 0 && t == 0) off[NNODES] = NEDGES;
}

__global__ void fill_k(const int* __restrict__ ei, int* __restrict__ cur,
                       int* __restrict__ srclist, int E) {
    int e = blockIdx.x * blockDim.x + threadIdx.x;
    if (e >= E) return;
    int src = ei[e];
    int dst = ei[E + e];
    int pos = atomicAdd(&cur[dst], 1);
    srclist[pos] = src;
}

// ---------------- bf16 helpers ----------------
__device__ __forceinline__ unsigned int bf16rne(float f) {
    unsigned int u = __float_as_uint(f);
    return (u + 0x7FFFu + ((u >> 16) & 1u)) >> 16;   // RNE (no NaN inputs)
}
__device__ __forceinline__ float bflo(unsigned int p) { return __uint_as_float(p << 16); }
__device__ __forceinline__ float bfhi(unsigned int p) { return __uint_as_float(p & 0xFFFF0000u); }

// pack x (f32) -> xb (bf16), 8 per thread
__global__ void cvt_k(const float4* __restrict__ x4, uint4* __restrict__ xb4, int n8) {
    int i = blockIdx.x * blockDim.x + threadIdx.x;
    if (i >= n8) return;
    float4 a = x4[2 * i], b = x4[2 * i + 1];
    uint4 o;
    o.x = bf16rne(a.x) | (bf16rne(a.y) << 16);
    o.y = bf16rne(a.z) | (bf16rne(a.w) << 16);
    o.z = bf16rne(b.x) | (bf16rne(b.y) << 16);
    o.w = bf16rne(b.z) | (bf16rne(b.w) << 16);
    xb4[i] = o;
}

// W [k][n] f32 -> Wt [n][k] bf16 (for MFMA B-fragments)
__global__ void cvtw_k(const float* __restrict__ W, u16* __restrict__ Wt) {
    int i = blockIdx.x * blockDim.x + threadIdx.x;
    if (i >= DIM * DIM) return;
    int n = i >> 7, k = i & 127;
    Wt[i] = (u16)bf16rne(W[k * DIM + n]);
}

// ---------------- gather aggregation (bf16 neighbor reads, f32 accumulate) ----------------
__global__ void gather_bf_k(const float4* __restrict__ x4, const uint4* __restrict__ xb4,
                            const int* __restrict__ off, const int* __restrict__ srclist,
                            float4* __restrict__ hp4) {
    int t = blockIdx.x * blockDim.x + threadIdx.x;
    int node = t >> 4;
    if (node >= NNODES) return;
    int lane = t & 15;
    float4 a0 = x4[(size_t)node * 32 + lane * 2];
    float4 a1 = x4[(size_t)node * 32 + lane * 2 + 1];
    int beg = off[node], end = off[node + 1];
    for (int j = beg; j < end; ++j) {
        int s = srclist[j];
        uint4 p = xb4[(size_t)s * 16 + lane];
        a0.x += bflo(p.x); a0.y += bfhi(p.x);
        a0.z += bflo(p.y); a0.w += bfhi(p.y);
        a1.x += bflo(p.z); a1.y += bfhi(p.z);
        a1.z += bflo(p.w); a1.w += bfhi(p.w);
    }
    hp4[(size_t)node * 32 + lane * 2]     = a0;
    hp4[(size_t)node * 32 + lane * 2 + 1] = a1;
}

// f32 gather fallback
__global__ void gather_k(const float4* __restrict__ x4, const int* __restrict__ off,
                         const int* __restrict__ srclist, float4* __restrict__ hp4) {
    int t = blockIdx.x * blockDim.x + threadIdx.x;
    int node = t >> 5;
    if (node >= NNODES) return;
    int lane = t & 31;
    float4 acc = x4[(size_t)node * 32 + lane];
    int beg = off[node], end = off[node + 1];
    for (int j = beg; j < end; ++j) {
        int s = srclist[j];
        float4 v = x4[(size_t)s * 32 + lane];
        acc.x += v.x; acc.y += v.y; acc.z += v.z; acc.w += v.w;
    }
    hp4[(size_t)node * 32 + lane] = acc;
}

// ---------------- fallback atomic scatter ----------------
__global__ void copy_k(const float4* __restrict__ src, float4* __restrict__ dst, int n4) {
    int i = blockIdx.x * blockDim.x + threadIdx.x;
    if (i < n4) dst[i] = src[i];
}

__global__ void scatter_k(const float4* __restrict__ x4, const int* __restrict__ ei,
                          float* __restrict__ hp, int E) {
    int t = blockIdx.x * blockDim.x + threadIdx.x;
    int e = t >> 5;
    if (e >= E) return;
    int lane = t & 31;
    int src = ei[e];
    int dst = ei[E + e];
    float4 v = x4[(size_t)src * 32 + lane];
    float* p = hp + (size_t)dst * DIM + lane * 4;
    unsafeAtomicAdd(p + 0, v.x);
    unsafeAtomicAdd(p + 1, v.y);
    unsafeAtomicAdd(p + 2, v.z);
    unsafeAtomicAdd(p + 3, v.w);
}

// ---------------- MFMA MLP ----------------
// 256 thr = 4 waves; block owns 64 rows; wave owns a 16-row stripe x 128 cols
// (8 accum tiles of 16x16, K=128 in 4 iters of mfma_f32_16x16x32_bf16).
// A layer1: f32 hpre from global, RNE-packed in-register (A[m=lane&15][k=quad*8+j]).
// B: pre-transposed bf16 W in global -> L1-resident (32 KB). h roundtrips through
// per-wave LDS (pitch 136: 4m mod 32 -> 2-way, free) to re-enter as layer-2 A-frags.
__launch_bounds__(256)
__global__ void mlp_mfma_k(const float* __restrict__ hp, float* __restrict__ outp,
                           const u16* __restrict__ w1t, const float* __restrict__ b1,
                           const u16* __restrict__ w2t, const float* __restrict__ b2) {
    __shared__ __align__(16) u16 Abuf[4][16][136];   // 17 KB

    const int tid = threadIdx.x;
    const int wv = tid >> 6, lane = tid & 63;
    const int quad = lane >> 4, msel = lane & 15;
    const int rowbase = blockIdx.x * 64 + wv * 16;
    int rowA = rowbase + msel;
    if (rowA >= NNODES) rowA = NNODES - 1;           // clamp; stores are predicated

    f32x4 acc[8];
    #pragma unroll
    for (int t = 0; t < 8; ++t) acc[t] = (f32x4){0.f, 0.f, 0.f, 0.f};

    // ---- layer 1 ----
    #pragma unroll
    for (int it = 0; it < 4; ++it) {
        const float* ap = hp + (size_t)rowA * DIM + it * 32 + quad * 8;
        float4 p0 = *(const float4*)ap;
        float4 p1 = *(const float4*)(ap + 4);
        short8 afr;
        afr[0] = (short)bf16rne(p0.x); afr[1] = (short)bf16rne(p0.y);
        afr[2] = (short)bf16rne(p0.z); afr[3] = (short)bf16rne(p0.w);
        afr[4] = (short)bf16rne(p1.x); afr[5] = (short)bf16rne(p1.y);
        afr[6] = (short)bf16rne(p1.z); afr[7] = (short)bf16rne(p1.w);
        #pragma unroll
        for (int t = 0; t < 8; ++t) {
            short8 bfr = *(const short8*)(w1t + (size_t)(t * 16 + msel) * DIM + it * 32 + quad * 8);
            acc[t] = __builtin_amdgcn_mfma_f32_16x16x32_bf16(afr, bfr, acc[t], 0, 0, 0);
        }
    }

    // epilogue 1: +b1, relu, bf16 -> Abuf in A-layout for layer 2
    #pragma unroll
    for (int t = 0; t < 8; ++t) {
        float bb = b1[t * 16 + msel];
        #pragma unroll
        for (int r = 0; r < 4; ++r) {
            float v = fmaxf(acc[t][r] + bb, 0.f);
            Abuf[wv][quad * 4 + r][t * 16 + msel] = (u16)bf16rne(v);
        }
    }
    __syncthreads();

    // ---- layer 2 ----
    #pragma unroll
    for (int t = 0; t < 8; ++t) acc[t] = (f32x4){0.f, 0.f, 0.f, 0.f};
    #pragma unroll
    for (int it = 0; it < 4; ++it) {
        short8 afr = *(const short8*)&Abuf[wv][msel][it * 32 + quad * 8];
        #pragma unroll
        for (int t = 0; t < 8; ++t) {
            short8 bfr = *(const short8*)(w2t + (size_t)(t * 16 + msel) * DIM + it * 32 + quad * 8);
            acc[t] = __builtin_amdgcn_mfma_f32_16x16x32_bf16(afr, bfr, acc[t], 0, 0, 0);
        }
    }

    // epilogue 2: +b2, store f32
    #pragma unroll
    for (int t = 0; t < 8; ++t) {
        float bb = b2[t * 16 + msel];
        #pragma unroll
        for (int r = 0; r < 4; ++r) {
            int row = rowbase + quad * 4 + r;
            if (row < NNODES)
                outp[(size_t)row * DIM + t * 16 + msel] = acc[t][r] + bb;
        }
    }
}

// f32 VALU MLP fallback (R5 config: 256 thr, 32 rows, 4x4 tile)
__launch_bounds__(256)
__global__ void mlp_k(float* __restrict__ io,
                      const float* __restrict__ W1, const float* __restrict__ b1,
                      const float* __restrict__ W2, const float* __restrict__ b2,
                      int N) {
    __shared__ float Wl[DIM * DIM];
    __shared__ float As[32][DIM];
    const int tid = threadIdx.x;
    const int r0 = blockIdx.x * 32;
    const int tc = tid & 31;
    const int tr = tid >> 5;
    {
        const float4* w4 = (const float4*)W1;
        float4* wl4 = (float4*)Wl;
        #pragma unroll
        for (int i = 0; i < 16; ++i) wl4[tid + i * 256] = w4[tid + i * 256];
    }
    {
        const float4* io4 = (const float4*)io;
        float4* as4 = (float4*)As;
        #pragma unroll
        for (int i = 0; i < 4; ++i) {
            int p = tid + i * 256;
            int row = p >> 5;
            float4 v = make_float4(0.f, 0.f, 0.f, 0.f);
            if (r0 + row < N) v = io4[(size_t)(r0 + row) * 32 + (p & 31)];
            as4[p] = v;
        }
    }
    __syncthreads();
    float acc[4][4];
    #pragma unroll
    for (int i = 0; i < 4; ++i)
        #pragma unroll
        for (int j = 0; j < 4; ++j) acc[i][j] = 0.f;
    for (int kc = 0; kc < 32; ++kc) {
        float4 a[4], w[4];
        #pragma unroll
        for (int i = 0; i < 4; ++i) a[i] = *(const float4*)&As[tr * 4 + i][kc * 4];
        #pragma unroll
        for (int kk = 0; kk < 4; ++kk) w[kk] = *(const float4*)&Wl[(kc * 4 + kk) * DIM + tc * 4];
        float af[4][4];
        #pragma unroll
        for (int i = 0; i < 4; ++i) {
            af[i][0] = a[i].x; af[i][1] = a[i].y; af[i][2] = a[i].z; af[i][3] = a[i].w;
        }
        #pragma unroll
        for (int kk = 0; kk < 4; ++kk) {
            float wv[4] = {w[kk].x, w[kk].y, w[kk].z, w[kk].w};
            #pragma unroll
            for (int i = 0; i < 4; ++i)
                #pragma unroll
                for (int j = 0; j < 4; ++j)
                    acc[i][j] = fmaf(af[i][kk], wv[j], acc[i][j]);
        }
    }
    float4 bv1 = ((const float4*)b1)[tc];
    float h[4][4];
    #pragma unroll
    for (int i = 0; i < 4; ++i) {
        h[i][0] = fmaxf(acc[i][0] + bv1.x, 0.f);
        h[i][1] = fmaxf(acc[i][1] + bv1.y, 0.f);
        h[i][2] = fmaxf(acc[i][2] + bv1.z, 0.f);
        h[i][3] = fmaxf(acc[i][3] + bv1.w, 0.f);
    }
    __syncthreads();
    {
        const float4* w4 = (const float4*)W2;
        float4* wl4 = (float4*)Wl;
        #pragma unroll
        for (int i = 0; i < 16; ++i) wl4[tid + i * 256] = w4[tid + i * 256];
    }
    #pragma unroll
    for (int i = 0; i < 4; ++i)
        *(float4*)&As[tr * 4 + i][tc * 4] = make_float4(h[i][0], h[i][1], h[i][2], h[i][3]);
    __syncthreads();
    #pragma unroll
    for (int i = 0; i < 4; ++i)
        #pragma unroll
        for (int j = 0; j < 4; ++j) acc[i][j] = 0.f;
    for (int kc = 0; kc < 32; ++kc) {
        float4 a[4], w[4];
        #pragma unroll
        for (int i = 0; i < 4; ++i) a[i] = *(const float4*)&As[tr * 4 + i][kc * 4];
        #pragma unroll
        for (int kk = 0; kk < 4; ++kk) w[kk] = *(const float4*)&Wl[(kc * 4 + kk) * DIM + tc * 4];
        float af[4][4];
        #pragma unroll
        for (int i = 0; i < 4; ++i) {
            af[i][0] = a[i].x; af[i][1] = a[i].y; af[i][2] = a[i].z; af[i][3] = a[i].w;
        }
        #pragma unroll
        for (int kk = 0; kk < 4; ++kk) {
            float wv[4] = {w[kk].x, w[kk].y, w[kk].z, w[kk].w};
            #pragma unroll
            for (int i = 0; i < 4; ++i)
                #pragma unroll
                for (int j = 0; j < 4; ++j)
                    acc[i][j] = fmaf(af[i][kk], wv[j], acc[i][j]);
        }
    }
    float4 bv2 = ((const float4*)b2)[tc];
    float4* io4 = (float4*)io;
    #pragma unroll
    for (int ri = 0; ri < 4; ++ri) {
        int row = r0 + tr * 4 + ri;
        if (row < N) {
            float4 o = make_float4(acc[ri][0] + bv2.x, acc[ri][1] + bv2.y,
                                   acc[ri][2] + bv2.z, acc[ri][3] + bv2.w);
            io4[(size_t)row * 32 + tc] = o;
        }
    }
}

extern "C" void kernel_launch(void* const* d_in, const int* in_sizes, int n_in,
                              void* d_out, int out_size, void* d_ws, size_t ws_size,
                              hipStream_t stream) {
    const float* x  = (const float*)d_in[0];
    const int*   ei = (const int*)d_in[1];
    const float* W1 = (const float*)d_in[2];
    const float* b1 = (const float*)d_in[3];
    const float* W2 = (const float*)d_in[4];
    const float* b2 = (const float*)d_in[5];
    float* out = (float*)d_out;

    // ws layout: xb[bf16 x, 12.8MB] | csr ints | w1t | w2t
    const size_t xb_bytes  = (size_t)NNODES * DIM * 2;
    const size_t csr_ints  = (size_t)(NNODES * 2 + (NNODES + 1) + NEDGES + 128);
    const size_t csr_bytes = (csr_ints * sizeof(int) + 15) & ~(size_t)15;
    const size_t wt_bytes  = (size_t)DIM * DIM * 2;
    const size_t need_csr  = csr_ints * sizeof(int);
    const size_t need_full = xb_bytes + csr_bytes + 2 * wt_bytes;

    if (ws_size >= need_csr) {
        bool full = (ws_size >= need_full);
        uint4* xb4 = nullptr;
        u16 *w1t = nullptr, *w2t = nullptr;
        int* ibase;
        if (full) {
            xb4 = (uint4*)d_ws;
            ibase = (int*)((char*)d_ws + xb_bytes);
            w1t = (u16*)((char*)d_ws + xb_bytes + csr_bytes);
            w2t = w1t + DIM * DIM;
        } else {
            ibase = (int*)d_ws;
        }
        int* deg = ibase;
        int* cur = deg + NNODES;
        int* off = cur + NNODES;
        int* srclist = off + NNODES + 1;
        int* bsum = srclist + NEDGES;
        int* bbase = bsum + 64;

        zero_k<<<(NNODES + 255) / 256, 256, 0, stream>>>(deg, NNODES);
        hist_k<<<(NEDGES + 255) / 256, 256, 0, stream>>>(ei, deg, NEDGES);
        scanA_k<<<SCAN_BLK, 256, 0, stream>>>(deg, bsum);
        scanB_k<<<1, 64, 0, stream>>>(bsum, bbase);
        scanC_k<<<SCAN_BLK, 256, 0, stream>>>(deg, bbase, off, cur);
        fill_k<<<(NEDGES + 255) / 256, 256, 0, stream>>>(ei, cur, srclist, NEDGES);

        if (full) {
            int n8 = NNODES * DIM / 8;
            cvt_k<<<(n8 + 255) / 256, 256, 0, stream>>>((const float4*)x, xb4, n8);
            cvtw_k<<<(DIM * DIM + 255) / 256, 256, 0, stream>>>(W1, w1t);
            cvtw_k<<<(DIM * DIM + 255) / 256, 256, 0, stream>>>(W2, w2t);
            int gthreads = NNODES * 16;
            gather_bf_k<<<(gthreads + 255) / 256, 256, 0, stream>>>(
                (const float4*)x, xb4, off, srclist, (float4*)out);
            mlp_mfma_k<<<(NNODES + 63) / 64, 256, 0, stream>>>(out, out, w1t, b1, w2t, b2);
        } else {
            int gthreads = NNODES * 32;
            gather_k<<<(gthreads + 255) / 256, 256, 0, stream>>>(
                (const float4*)x, off, srclist, (float4*)out);
            mlp_k<<<(NNODES + 31) / 32, 256, 0, stream>>>(out, W1, b1, W2, b2, NNODES);
        }
    } else {
        int n4 = NNODES * DIM / 4;
        copy_k<<<(n4 + 255) / 256, 256, 0, stream>>>((const float4*)x, (float4*)out, n4);
        int sthreads = NEDGES * 32;
        scatter_k<<<(sthreads + 255) / 256, 256, 0, stream>>>((const float4*)x, ei, out, NEDGES);
        mlp_k<<<(NNODES + 31) / 32, 256, 0, stream>>>(out, W1, b1, W2, b2, NNODES);
    }
}

// Round 8
// 218.035 us; speedup vs baseline: 1.2730x; 1.0889x over previous
//
#include <hip/hip_runtime.h>

#define NNODES 50000
#define NEDGES 640000
#define DIM 128
#define SCAN_BLK 49   // ceil(50000 / 1024)

typedef unsigned short u16;
typedef __attribute__((ext_vector_type(8))) short short8;   // 8 bf16 (4 VGPRs)
typedef __attribute__((ext_vector_type(4))) float f32x4;

// ---------------- bf16 helpers ----------------
__device__ __forceinline__ unsigned int bf16rne(float f) {
    unsigned int u = __float_as_uint(f);
    return (u + 0x7FFFu + ((u >> 16) & 1u)) >> 16;   // RNE (no NaN inputs)
}
__device__ __forceinline__ float bflo(unsigned int p) { return __uint_as_float(p << 16); }
__device__ __forceinline__ float bfhi(unsigned int p) { return __uint_as_float(p & 0xFFFF0000u); }

// ---------------- fused prep: cvt x -> bf16 | cvt W1,W2 -> bf16^T | zero deg ----------------
#define CVT_BLKS   3125   // 800000 uint4 / 256
#define CVTW_BLKS  128    // 32768 / 256
#define ZERO_BLKS  196    // 50000 / 256 ceil
__global__ void prep_k(const float4* __restrict__ x4, uint4* __restrict__ xb4,
                       const float* __restrict__ W1, const float* __restrict__ W2,
                       u16* __restrict__ wt, int* __restrict__ deg) {
    const int b = blockIdx.x, t = threadIdx.x;
    if (b < CVT_BLKS) {
        int i = b * 256 + t;                       // < 800000
        float4 a = x4[2 * i], c = x4[2 * i + 1];
        uint4 o;
        o.x = bf16rne(a.x) | (bf16rne(a.y) << 16);
        o.y = bf16rne(a.z) | (bf16rne(a.w) << 16);
        o.z = bf16rne(c.x) | (bf16rne(c.y) << 16);
        o.w = bf16rne(c.z) | (bf16rne(c.w) << 16);
        xb4[i] = o;
    } else if (b < CVT_BLKS + CVTW_BLKS) {
        int i = (b - CVT_BLKS) * 256 + t;          // < 32768
        const float* W = (i < DIM * DIM) ? W1 : W2;
        int li = i & (DIM * DIM - 1);
        int n = li >> 7, k = li & 127;
        wt[i] = (u16)bf16rne(W[k * DIM + n]);
    } else {
        int i = (b - CVT_BLKS - CVTW_BLKS) * 256 + t;
        if (i < NNODES) deg[i] = 0;
    }
}

// ---------------- CSR build ----------------
__global__ void zero_k(int* __restrict__ p, int n) {
    int i = blockIdx.x * blockDim.x + threadIdx.x;
    if (i < n) p[i] = 0;
}

__global__ void hist_k(const int* __restrict__ ei, int* __restrict__ deg, int E) {
    int e = blockIdx.x * blockDim.x + threadIdx.x;
    if (e < E) atomicAdd(&deg[ei[E + e]], 1);
}

__global__ void scanA_k(const int* __restrict__ deg, int* __restrict__ bsum) {
    const int t = threadIdx.x, b = blockIdx.x;
    const int base = b * 1024 + t * 4;
    int4 v = make_int4(0, 0, 0, 0);
    if (base < NNODES) v = *(const int4*)&deg[base];
    int s = v.x + v.y + v.z + v.w;
    #pragma unroll
    for (int d = 32; d > 0; d >>= 1) s += __shfl_down(s, d, 64);
    __shared__ int ws[4];
    if ((t & 63) == 0) ws[t >> 6] = s;
    __syncthreads();
    if (t == 0) bsum[b] = ws[0] + ws[1] + ws[2] + ws[3];
}

// per-block exclusive scan; each block derives its own base from bsum (scanB folded in)
__global__ void scanC_k(const int* __restrict__ deg, const int* __restrict__ bsum,
                        int* __restrict__ off, int* __restrict__ cur) {
    __shared__ int ws[4];
    __shared__ int sbase;
    const int t = threadIdx.x, b = blockIdx.x;
    if (t < 64) {
        int v = (t < SCAN_BLK && t < b) ? bsum[t] : 0;
        #pragma unroll
        for (int d = 32; d > 0; d >>= 1) v += __shfl_down(v, d, 64);
        if (t == 0) sbase = v;
    }
    const int base = b * 1024 + t * 4;
    int4 v = make_int4(0, 0, 0, 0);
    if (base < NNODES) v = *(const int4*)&deg[base];
    const int s = v.x + v.y + v.z + v.w;
    const int lane = t & 63, w = t >> 6;
    int sv = s;
    #pragma unroll
    for (int d = 1; d < 64; d <<= 1) {
        int u = __shfl_up(sv, d, 64);
        if (lane >= d) sv += u;
    }
    if (lane == 63) ws[w] = sv;
    __syncthreads();
    int wbase = 0;
    #pragma unroll
    for (int i = 0; i < 4; ++i) if (i < w) wbase += ws[i];
    int ex = sbase + wbase + (sv - s);
    if (base < NNODES) {
        int4 o;
        o.x = ex;
        o.y = o.x + v.x;
        o.z = o.y + v.y;
        o.w = o.z + v.z;
        *(int4*)&off[base] = o;
        *(int4*)&cur[base] = o;
    }
    if (b == 0 && t == 0) off[NNODES] = NEDGES;
}

__global__ void fill_k(const int* __restrict__ ei, int* __restrict__ cur,
                       int* __restrict__ srclist, int E) {
    int e = blockIdx.x * blockDim.x + threadIdx.x;
    if (e >= E) return;
    int src = ei[e];
    int dst = ei[E + e];
    int pos = atomicAdd(&cur[dst], 1);
    srclist[pos] = src;
}

// ---------------- gather: bf16 rows, f32 accumulate, bf16 hpre out, unroll 4 ----------------
__global__ void gather_bf_k(const float4* __restrict__ x4, const uint4* __restrict__ xb4,
                            const int* __restrict__ off, const int* __restrict__ srclist,
                            uint4* __restrict__ hpb4) {
    int t = blockIdx.x * blockDim.x + threadIdx.x;
    int node = t >> 4;
    if (node >= NNODES) return;
    int lane = t & 15;
    float4 a0 = x4[(size_t)node * 32 + lane * 2];
    float4 a1 = x4[(size_t)node * 32 + lane * 2 + 1];
    int beg = off[node], end = off[node + 1];
    int j = beg;
    for (; j + 3 < end; j += 4) {
        int s0 = srclist[j], s1 = srclist[j + 1], s2 = srclist[j + 2], s3 = srclist[j + 3];
        uint4 p0 = xb4[(size_t)s0 * 16 + lane];
        uint4 p1 = xb4[(size_t)s1 * 16 + lane];
        uint4 p2 = xb4[(size_t)s2 * 16 + lane];
        uint4 p3 = xb4[(size_t)s3 * 16 + lane];
        a0.x += bflo(p0.x) + bflo(p1.x) + bflo(p2.x) + bflo(p3.x);
        a0.y += bfhi(p0.x) + bfhi(p1.x) + bfhi(p2.x) + bfhi(p3.x);
        a0.z += bflo(p0.y) + bflo(p1.y) + bflo(p2.y) + bflo(p3.y);
        a0.w += bfhi(p0.y) + bfhi(p1.y) + bfhi(p2.y) + bfhi(p3.y);
        a1.x += bflo(p0.z) + bflo(p1.z) + bflo(p2.z) + bflo(p3.z);
        a1.y += bfhi(p0.z) + bfhi(p1.z) + bfhi(p2.z) + bfhi(p3.z);
        a1.z += bflo(p0.w) + bflo(p1.w) + bflo(p2.w) + bflo(p3.w);
        a1.w += bfhi(p0.w) + bfhi(p1.w) + bfhi(p2.w) + bfhi(p3.w);
    }
    for (; j < end; ++j) {
        int s = srclist[j];
        uint4 p = xb4[(size_t)s * 16 + lane];
        a0.x += bflo(p.x); a0.y += bfhi(p.x);
        a0.z += bflo(p.y); a0.w += bfhi(p.y);
        a1.x += bflo(p.z); a1.y += bfhi(p.z);
        a1.z += bflo(p.w); a1.w += bfhi(p.w);
    }
    uint4 o;
    o.x = bf16rne(a0.x) | (bf16rne(a0.y) << 16);
    o.y = bf16rne(a0.z) | (bf16rne(a0.w) << 16);
    o.z = bf16rne(a1.x) | (bf16rne(a1.y) << 16);
    o.w = bf16rne(a1.z) | (bf16rne(a1.w) << 16);
    hpb4[(size_t)node * 16 + lane] = o;
}

// f32 gather fallback (writes f32 hpre into io)
__global__ void gather_k(const float4* __restrict__ x4, const int* __restrict__ off,
                         const int* __restrict__ srclist, float4* __restrict__ hp4) {
    int t = blockIdx.x * blockDim.x + threadIdx.x;
    int node = t >> 5;
    if (node >= NNODES) return;
    int lane = t & 31;
    float4 acc = x4[(size_t)node * 32 + lane];
    int beg = off[node], end = off[node + 1];
    for (int j = beg; j < end; ++j) {
        int s = srclist[j];
        float4 v = x4[(size_t)s * 32 + lane];
        acc.x += v.x; acc.y += v.y; acc.z += v.z; acc.w += v.w;
    }
    hp4[(size_t)node * 32 + lane] = acc;
}

// ---------------- fallback atomic scatter ----------------
__global__ void copy_k(const float4* __restrict__ src, float4* __restrict__ dst, int n4) {
    int i = blockIdx.x * blockDim.x + threadIdx.x;
    if (i < n4) dst[i] = src[i];
}

__global__ void scatter_k(const float4* __restrict__ x4, const int* __restrict__ ei,
                          float* __restrict__ hp, int E) {
    int t = blockIdx.x * blockDim.x + threadIdx.x;
    int e = t >> 5;
    if (e >= E) return;
    int lane = t & 31;
    int src = ei[e];
    int dst = ei[E + e];
    float4 v = x4[(size_t)src * 32 + lane];
    float* p = hp + (size_t)dst * DIM + lane * 4;
    unsafeAtomicAdd(p + 0, v.x);
    unsafeAtomicAdd(p + 1, v.y);
    unsafeAtomicAdd(p + 2, v.z);
    unsafeAtomicAdd(p + 3, v.w);
}

// ---------------- MFMA MLP (A from bf16 hpre, direct short8 loads) ----------------
__launch_bounds__(256)
__global__ void mlp_mfma_k(const u16* __restrict__ hpb, float* __restrict__ outp,
                           const u16* __restrict__ w1t, const float* __restrict__ b1,
                           const u16* __restrict__ w2t, const float* __restrict__ b2) {
    __shared__ __align__(16) u16 Abuf[4][16][136];   // 17 KB; pitch 136 -> 2-way max (free)

    const int tid = threadIdx.x;
    const int wv = tid >> 6, lane = tid & 63;
    const int quad = lane >> 4, msel = lane & 15;
    const int rowbase = blockIdx.x * 64 + wv * 16;
    int rowA = rowbase + msel;
    if (rowA >= NNODES) rowA = NNODES - 1;           // clamp; stores predicated

    f32x4 acc[8];
    #pragma unroll
    for (int t = 0; t < 8; ++t) acc[t] = (f32x4){0.f, 0.f, 0.f, 0.f};

    // ---- layer 1 ----
    #pragma unroll
    for (int it = 0; it < 4; ++it) {
        short8 afr = *(const short8*)(hpb + (size_t)rowA * DIM + it * 32 + quad * 8);
        #pragma unroll
        for (int t = 0; t < 8; ++t) {
            short8 bfr = *(const short8*)(w1t + (size_t)(t * 16 + msel) * DIM + it * 32 + quad * 8);
            acc[t] = __builtin_amdgcn_mfma_f32_16x16x32_bf16(afr, bfr, acc[t], 0, 0, 0);
        }
    }

    // epilogue 1: +b1, relu, bf16 -> Abuf (A-layout for layer 2)
    #pragma unroll
    for (int t = 0; t < 8; ++t) {
        float bb = b1[t * 16 + msel];
        #pragma unroll
        for (int r = 0; r < 4; ++r) {
            float v = fmaxf(acc[t][r] + bb, 0.f);
            Abuf[wv][quad * 4 + r][t * 16 + msel] = (u16)bf16rne(v);
        }
    }
    __syncthreads();

    // ---- layer 2 ----
    #pragma unroll
    for (int t = 0; t < 8; ++t) acc[t] = (f32x4){0.f, 0.f, 0.f, 0.f};
    #pragma unroll
    for (int it = 0; it < 4; ++it) {
        short8 afr = *(const short8*)&Abuf[wv][msel][it * 32 + quad * 8];
        #pragma unroll
        for (int t = 0; t < 8; ++t) {
            short8 bfr = *(const short8*)(w2t + (size_t)(t * 16 + msel) * DIM + it * 32 + quad * 8);
            acc[t] = __builtin_amdgcn_mfma_f32_16x16x32_bf16(afr, bfr, acc[t], 0, 0, 0);
        }
    }

    // epilogue 2: +b2, store f32
    #pragma unroll
    for (int t = 0; t < 8; ++t) {
        float bb = b2[t * 16 + msel];
        #pragma unroll
        for (int r = 0; r < 4; ++r) {
            int row = rowbase + quad * 4 + r;
            if (row < NNODES)
                outp[(size_t)row * DIM + t * 16 + msel] = acc[t][r] + bb;
        }
    }
}

// f32 VALU MLP fallback
__launch_bounds__(256)
__global__ void mlp_k(float* __restrict__ io,
                      const float* __restrict__ W1, const float* __restrict__ b1,
                      const float* __restrict__ W2, const float* __restrict__ b2,
                      int N) {
    __shared__ float Wl[DIM * DIM];
    __shared__ float As[32][DIM];
    const int tid = threadIdx.x;
    const int r0 = blockIdx.x * 32;
    const int tc = tid & 31;
    const int tr = tid >> 5;
    {
        const float4* w4 = (const float4*)W1;
        float4* wl4 = (float4*)Wl;
        #pragma unroll
        for (int i = 0; i < 16; ++i) wl4[tid + i * 256] = w4[tid + i * 256];
    }
    {
        const float4* io4 = (const float4*)io;
        float4* as4 = (float4*)As;
        #pragma unroll
        for (int i = 0; i < 4; ++i) {
            int p = tid + i * 256;
            int row = p >> 5;
            float4 v = make_float4(0.f, 0.f, 0.f, 0.f);
            if (r0 + row < N) v = io4[(size_t)(r0 + row) * 32 + (p & 31)];
            as4[p] = v;
        }
    }
    __syncthreads();
    float acc[4][4];
    #pragma unroll
    for (int i = 0; i < 4; ++i)
        #pragma unroll
        for (int j = 0; j < 4; ++j) acc[i][j] = 0.f;
    for (int kc = 0; kc < 32; ++kc) {
        float4 a[4], w[4];
        #pragma unroll
        for (int i = 0; i < 4; ++i) a[i] = *(const float4*)&As[tr * 4 + i][kc * 4];
        #pragma unroll
        for (int kk = 0; kk < 4; ++kk) w[kk] = *(const float4*)&Wl[(kc * 4 + kk) * DIM + tc * 4];
        float af[4][4];
        #pragma unroll
        for (int i = 0; i < 4; ++i) {
            af[i][0] = a[i].x; af[i][1] = a[i].y; af[i][2] = a[i].z; af[i][3] = a[i].w;
        }
        #pragma unroll
        for (int kk = 0; kk < 4; ++kk) {
            float wv[4] = {w[kk].x, w[kk].y, w[kk].z, w[kk].w};
            #pragma unroll
            for (int i = 0; i < 4; ++i)
                #pragma unroll
                for (int j = 0; j < 4; ++j)
                    acc[i][j] = fmaf(af[i][kk], wv[j], acc[i][j]);
        }
    }
    float4 bv1 = ((const float4*)b1)[tc];
    float h[4][4];
    #pragma unroll
    for (int i = 0; i < 4; ++i) {
        h[i][0] = fmaxf(acc[i][0] + bv1.x, 0.f);
        h[i][1] = fmaxf(acc[i][1] + bv1.y, 0.f);
        h[i][2] = fmaxf(acc[i][2] + bv1.z, 0.f);
        h[i][3] = fmaxf(acc[i][3] + bv1.w, 0.f);
    }
    __syncthreads();
    {
        const float4* w4 = (const float4*)W2;
        float4* wl4 = (float4*)Wl;
        #pragma unroll
        for (int i = 0; i < 16; ++i) wl4[tid + i * 256] = w4[tid + i * 256];
    }
    #pragma unroll
    for (int i = 0; i < 4; ++i)
        *(float4*)&As[tr * 4 + i][tc * 4] = make_float4(h[i][0], h[i][1], h[i][2], h[i][3]);
    __syncthreads();
    #pragma unroll
    for (int i = 0; i < 4; ++i)
        #pragma unroll
        for (int j = 0; j < 4; ++j) acc[i][j] = 0.f;
    for (int kc = 0; kc < 32; ++kc) {
        float4 a[4], w[4];
        #pragma unroll
        for (int i = 0; i < 4; ++i) a[i] = *(const float4*)&As[tr * 4 + i][kc * 4];
        #pragma unroll
        for (int kk = 0; kk < 4; ++kk) w[kk] = *(const float4*)&Wl[(kc * 4 + kk) * DIM + tc * 4];
        float af[4][4];
        #pragma unroll
        for (int i = 0; i < 4; ++i) {
            af[i][0] = a[i].x; af[i][1] = a[i].y; af[i][2] = a[i].z; af[i][3] = a[i].w;
        }
        #pragma unroll
        for (int kk = 0; kk < 4; ++kk) {
            float wv[4] = {w[kk].x, w[kk].y, w[kk].z, w[kk].w};
            #pragma unroll
            for (int i = 0; i < 4; ++i)
                #pragma unroll
                for (int j = 0; j < 4; ++j)
                    acc[i][j] = fmaf(af[i][kk], wv[j], acc[i][j]);
        }
    }
    float4 bv2 = ((const float4*)b2)[tc];
    float4* io4 = (float4*)io;
    #pragma unroll
    for (int ri = 0; ri < 4; ++ri) {
        int row = r0 + tr * 4 + ri;
        if (row < N) {
            float4 o = make_float4(acc[ri][0] + bv2.x, acc[ri][1] + bv2.y,
                                   acc[ri][2] + bv2.z, acc[ri][3] + bv2.w);
            io4[(size_t)row * 32 + tc] = o;
        }
    }
}

extern "C" void kernel_launch(void* const* d_in, const int* in_sizes, int n_in,
                              void* d_out, int out_size, void* d_ws, size_t ws_size,
                              hipStream_t stream) {
    const float* x  = (const float*)d_in[0];
    const int*   ei = (const int*)d_in[1];
    const float* W1 = (const float*)d_in[2];
    const float* b1 = (const float*)d_in[3];
    const float* W2 = (const float*)d_in[4];
    const float* b2 = (const float*)d_in[5];
    float* out = (float*)d_out;

    // ws layout: xb[12.8MB] | hpb[12.8MB] | csr ints | w1t|w2t
    const size_t xb_bytes  = (size_t)NNODES * DIM * 2;
    const size_t hp_bytes  = (size_t)NNODES * DIM * 2;
    const size_t csr_ints  = (size_t)(NNODES * 2 + (NNODES + 1) + NEDGES + 128);
    const size_t csr_bytes = (csr_ints * sizeof(int) + 15) & ~(size_t)15;
    const size_t wt_bytes  = (size_t)DIM * DIM * 2;
    const size_t need_csr  = csr_ints * sizeof(int);
    const size_t need_full = xb_bytes + hp_bytes + csr_bytes + 2 * wt_bytes;

    if (ws_size >= need_full) {
        uint4* xb4  = (uint4*)d_ws;
        uint4* hpb4 = (uint4*)((char*)d_ws + xb_bytes);
        int*   deg  = (int*)((char*)d_ws + xb_bytes + hp_bytes);
        int*   cur  = deg + NNODES;
        int*   off  = cur + NNODES;
        int*   srclist = off + NNODES + 1;
        int*   bsum = srclist + NEDGES;
        u16*   w1t  = (u16*)((char*)d_ws + xb_bytes + hp_bytes + csr_bytes);
        u16*   w2t  = w1t + DIM * DIM;

        prep_k<<<CVT_BLKS + CVTW_BLKS + ZERO_BLKS, 256, 0, stream>>>(
            (const float4*)x, xb4, W1, W2, w1t, deg);
        hist_k<<<(NEDGES + 255) / 256, 256, 0, stream>>>(ei, deg, NEDGES);
        scanA_k<<<SCAN_BLK, 256, 0, stream>>>(deg, bsum);
        scanC_k<<<SCAN_BLK, 256, 0, stream>>>(deg, bsum, off, cur);
        fill_k<<<(NEDGES + 255) / 256, 256, 0, stream>>>(ei, cur, srclist, NEDGES);
        gather_bf_k<<<(NNODES * 16 + 255) / 256, 256, 0, stream>>>(
            (const float4*)x, xb4, off, srclist, hpb4);
        mlp_mfma_k<<<(NNODES + 63) / 64, 256, 0, stream>>>(
            (const u16*)hpb4, out, w1t, b1, w2t, b2);
    } else if (ws_size >= need_csr) {
        int* deg = (int*)d_ws;
        int* cur = deg + NNODES;
        int* off = cur + NNODES;
        int* srclist = off + NNODES + 1;
        int* bsum = srclist + NEDGES;
        zero_k<<<(NNODES + 255) / 256, 256, 0, stream>>>(deg, NNODES);
        hist_k<<<(NEDGES + 255) / 256, 256, 0, stream>>>(ei, deg, NEDGES);
        scanA_k<<<SCAN_BLK, 256, 0, stream>>>(deg, bsum);
        scanC_k<<<SCAN_BLK, 256, 0, stream>>>(deg, bsum, off, cur);
        fill_k<<<(NEDGES + 255) / 256, 256, 0, stream>>>(ei, cur, srclist, NEDGES);
        gather_k<<<(NNODES * 32 + 255) / 256, 256, 0, stream>>>(
            (const float4*)x, off, srclist, (float4*)out);
        mlp_k<<<(NNODES + 31) / 32, 256, 0, stream>>>(out, W1, b1, W2, b2, NNODES);
    } else {
        int n4 = NNODES * DIM / 4;
        copy_k<<<(n4 + 255) / 256, 256, 0, stream>>>((const float4*)x, (float4*)out, n4);
        scatter_k<<<(NEDGES * 32 + 255) / 256, 256, 0, stream>>>((const float4*)x, ei, out, NEDGES);
        mlp_k<<<(NNODES + 31) / 32, 256, 0, stream>>>(out, W1, b1, W2, b2, NNODES);
    }
}

// Round 9
// 194.310 us; speedup vs baseline: 1.4284x; 1.1221x over previous
//
#include <hip/hip_runtime.h>

#define NNODES 50000
#define NEDGES 640000
#define DIM 128
#define SCAN_BLK 49   // ceil(50000 / 1024)

typedef unsigned short u16;
typedef __attribute__((ext_vector_type(8))) short short8;   // 8 bf16 (4 VGPRs)
typedef __attribute__((ext_vector_type(4))) float f32x4;

// ---------------- bf16 helpers ----------------
__device__ __forceinline__ unsigned int bf16rne(float f) {
    unsigned int u = __float_as_uint(f);
    return (u + 0x7FFFu + ((u >> 16) & 1u)) >> 16;   // RNE (no NaN inputs)
}
__device__ __forceinline__ float bflo(unsigned int p) { return __uint_as_float(p << 16); }
__device__ __forceinline__ float bfhi(unsigned int p) { return __uint_as_float(p & 0xFFFF0000u); }

// ---------------- fused prep: cvt x -> bf16 | cvt W1,W2 -> bf16^T | head = -1 ----------------
#define CVT_BLKS   3125   // 800000 uint4 / 256
#define CVTW_BLKS  128    // 32768 / 256
#define HEAD_BLKS  196    // ceil(50000 / 256)
__global__ void prep_k(const float4* __restrict__ x4, uint4* __restrict__ xb4,
                       const float* __restrict__ W1, const float* __restrict__ W2,
                       u16* __restrict__ wt, int* __restrict__ head) {
    const int b = blockIdx.x, t = threadIdx.x;
    if (b < CVT_BLKS) {
        int i = b * 256 + t;                       // < 800000
        float4 a = x4[2 * i], c = x4[2 * i + 1];
        uint4 o;
        o.x = bf16rne(a.x) | (bf16rne(a.y) << 16);
        o.y = bf16rne(a.z) | (bf16rne(a.w) << 16);
        o.z = bf16rne(c.x) | (bf16rne(c.y) << 16);
        o.w = bf16rne(c.z) | (bf16rne(c.w) << 16);
        xb4[i] = o;
    } else if (b < CVT_BLKS + CVTW_BLKS) {
        int i = (b - CVT_BLKS) * 256 + t;          // < 32768
        const float* W = (i < DIM * DIM) ? W1 : W2;
        int li = i & (DIM * DIM - 1);
        int n = li >> 7, k = li & 127;
        wt[i] = (u16)bf16rne(W[k * DIM + n]);
    } else {
        int i = (b - CVT_BLKS - CVTW_BLKS) * 256 + t;
        if (i < NNODES) head[i] = -1;
    }
}

// ---------------- linked-list adjacency build (replaces hist/scan/fill) ----------------
// nextsrc[e] = {src, prev_head}; head[dst] = e. Payload store is coalesced by e.
__global__ void fill_ll_k(const int* __restrict__ ei, int* __restrict__ head,
                          int2* __restrict__ nextsrc, int E) {
    int e = blockIdx.x * blockDim.x + threadIdx.x;
    if (e >= E) return;
    int src = ei[e];
    int dst = ei[E + e];
    int old = atomicExch(&head[dst], e);
    nextsrc[e] = make_int2(src, old);
}

// ---------------- gather via chain walk: bf16 rows, f32 accumulate, bf16 hpre out ----------------
// 16 lanes per node. Per hop: one broadcast 8B read (chain) + one 16B/lane row read.
// Row fetch overlaps the next chain hop (independent given p).
__global__ void gather_ll_k(const float4* __restrict__ x4, const uint4* __restrict__ xb4,
                            const int* __restrict__ head, const int2* __restrict__ nextsrc,
                            uint4* __restrict__ hpb4) {
    int t = blockIdx.x * blockDim.x + threadIdx.x;
    int node = t >> 4;
    if (node >= NNODES) return;
    int lane = t & 15;
    float4 a0 = x4[(size_t)node * 32 + lane * 2];
    float4 a1 = x4[(size_t)node * 32 + lane * 2 + 1];
    int j = head[node];
    while (j >= 0) {
        int2 p = nextsrc[j];
        uint4 q = xb4[(size_t)p.x * 16 + lane];
        j = p.y;
        a0.x += bflo(q.x); a0.y += bfhi(q.x);
        a0.z += bflo(q.y); a0.w += bfhi(q.y);
        a1.x += bflo(q.z); a1.y += bfhi(q.z);
        a1.z += bflo(q.w); a1.w += bfhi(q.w);
    }
    uint4 o;
    o.x = bf16rne(a0.x) | (bf16rne(a0.y) << 16);
    o.y = bf16rne(a0.z) | (bf16rne(a0.w) << 16);
    o.z = bf16rne(a1.x) | (bf16rne(a1.y) << 16);
    o.w = bf16rne(a1.z) | (bf16rne(a1.w) << 16);
    hpb4[(size_t)node * 16 + lane] = o;
}

// ---------------- MFMA MLP (A from bf16 hpre, direct short8 loads) ----------------
__launch_bounds__(256)
__global__ void mlp_mfma_k(const u16* __restrict__ hpb, float* __restrict__ outp,
                           const u16* __restrict__ w1t, const float* __restrict__ b1,
                           const u16* __restrict__ w2t, const float* __restrict__ b2) {
    __shared__ __align__(16) u16 Abuf[4][16][136];   // 17 KB; pitch 136 -> 2-way max (free)

    const int tid = threadIdx.x;
    const int wv = tid >> 6, lane = tid & 63;
    const int quad = lane >> 4, msel = lane & 15;
    const int rowbase = blockIdx.x * 64 + wv * 16;
    int rowA = rowbase + msel;
    if (rowA >= NNODES) rowA = NNODES - 1;           // clamp; stores predicated

    f32x4 acc[8];
    #pragma unroll
    for (int t = 0; t < 8; ++t) acc[t] = (f32x4){0.f, 0.f, 0.f, 0.f};

    // ---- layer 1 ----
    #pragma unroll
    for (int it = 0; it < 4; ++it) {
        short8 afr = *(const short8*)(hpb + (size_t)rowA * DIM + it * 32 + quad * 8);
        #pragma unroll
        for (int t = 0; t < 8; ++t) {
            short8 bfr = *(const short8*)(w1t + (size_t)(t * 16 + msel) * DIM + it * 32 + quad * 8);
            acc[t] = __builtin_amdgcn_mfma_f32_16x16x32_bf16(afr, bfr, acc[t], 0, 0, 0);
        }
    }

    // epilogue 1: +b1, relu, bf16 -> Abuf (A-layout for layer 2)
    #pragma unroll
    for (int t = 0; t < 8; ++t) {
        float bb = b1[t * 16 + msel];
        #pragma unroll
        for (int r = 0; r < 4; ++r) {
            float v = fmaxf(acc[t][r] + bb, 0.f);
            Abuf[wv][quad * 4 + r][t * 16 + msel] = (u16)bf16rne(v);
        }
    }
    __syncthreads();

    // ---- layer 2 ----
    #pragma unroll
    for (int t = 0; t < 8; ++t) acc[t] = (f32x4){0.f, 0.f, 0.f, 0.f};
    #pragma unroll
    for (int it = 0; it < 4; ++it) {
        short8 afr = *(const short8*)&Abuf[wv][msel][it * 32 + quad * 8];
        #pragma unroll
        for (int t = 0; t < 8; ++t) {
            short8 bfr = *(const short8*)(w2t + (size_t)(t * 16 + msel) * DIM + it * 32 + quad * 8);
            acc[t] = __builtin_amdgcn_mfma_f32_16x16x32_bf16(afr, bfr, acc[t], 0, 0, 0);
        }
    }

    // epilogue 2: +b2, store f32
    #pragma unroll
    for (int t = 0; t < 8; ++t) {
        float bb = b2[t * 16 + msel];
        #pragma unroll
        for (int r = 0; r < 4; ++r) {
            int row = rowbase + quad * 4 + r;
            if (row < NNODES)
                outp[(size_t)row * DIM + t * 16 + msel] = acc[t][r] + bb;
        }
    }
}

// ================= fallback paths (smaller ws) =================

__global__ void zero_k(int* __restrict__ p, int n) {
    int i = blockIdx.x * blockDim.x + threadIdx.x;
    if (i < n) p[i] = 0;
}

__global__ void hist_k(const int* __restrict__ ei, int* __restrict__ deg, int E) {
    int e = blockIdx.x * blockDim.x + threadIdx.x;
    if (e < E) atomicAdd(&deg[ei[E + e]], 1);
}

__global__ void scanA_k(const int* __restrict__ deg, int* __restrict__ bsum) {
    const int t = threadIdx.x, b = blockIdx.x;
    const int base = b * 1024 + t * 4;
    int4 v = make_int4(0, 0, 0, 0);
    if (base < NNODES) v = *(const int4*)&deg[base];
    int s = v.x + v.y + v.z + v.w;
    #pragma unroll
    for (int d = 32; d > 0; d >>= 1) s += __shfl_down(s, d, 64);
    __shared__ int ws[4];
    if ((t & 63) == 0) ws[t >> 6] = s;
    __syncthreads();
    if (t == 0) bsum[b] = ws[0] + ws[1] + ws[2] + ws[3];
}

__global__ void scanC_k(const int* __restrict__ deg, const int* __restrict__ bsum,
                        int* __restrict__ off, int* __restrict__ cur) {
    __shared__ int ws[4];
    __shared__ int sbase;
    const int t = threadIdx.x, b = blockIdx.x;
    if (t < 64) {
        int v = (t < SCAN_BLK && t < b) ? bsum[t] : 0;
        #pragma unroll
        for (int d = 32; d > 0; d >>= 1) v += __shfl_down(v, d, 64);
        if (t == 0) sbase = v;
    }
    const int base = b * 1024 + t * 4;
    int4 v = make_int4(0, 0, 0, 0);
    if (base < NNODES) v = *(const int4*)&deg[base];
    const int s = v.x + v.y + v.z + v.w;
    const int lane = t & 63, w = t >> 6;
    int sv = s;
    #pragma unroll
    for (int d = 1; d < 64; d <<= 1) {
        int u = __shfl_up(sv, d, 64);
        if (lane >= d) sv += u;
    }
    if (lane == 63) ws[w] = sv;
    __syncthreads();
    int wbase = 0;
    #pragma unroll
    for (int i = 0; i < 4; ++i) if (i < w) wbase += ws[i];
    int ex = sbase + wbase + (sv - s);
    if (base < NNODES) {
        int4 o;
        o.x = ex;
        o.y = o.x + v.x;
        o.z = o.y + v.y;
        o.w = o.z + v.z;
        *(int4*)&off[base] = o;
        *(int4*)&cur[base] = o;
    }
    if (b == 0 && t == 0) off[NNODES] = NEDGES;
}

__global__ void fill_k(const int* __restrict__ ei, int* __restrict__ cur,
                       int* __restrict__ srclist, int E) {
    int e = blockIdx.x * blockDim.x + threadIdx.x;
    if (e >= E) return;
    int src = ei[e];
    int dst = ei[E + e];
    int pos = atomicAdd(&cur[dst], 1);
    srclist[pos] = src;
}

__global__ void gather_k(const float4* __restrict__ x4, const int* __restrict__ off,
                         const int* __restrict__ srclist, float4* __restrict__ hp4) {
    int t = blockIdx.x * blockDim.x + threadIdx.x;
    int node = t >> 5;
    if (node >= NNODES) return;
    int lane = t & 31;
    float4 acc = x4[(size_t)node * 32 + lane];
    int beg = off[node], end = off[node + 1];
    for (int j = beg; j < end; ++j) {
        int s = srclist[j];
        float4 v = x4[(size_t)s * 32 + lane];
        acc.x += v.x; acc.y += v.y; acc.z += v.z; acc.w += v.w;
    }
    hp4[(size_t)node * 32 + lane] = acc;
}

__global__ void copy_k(const float4* __restrict__ src, float4* __restrict__ dst, int n4) {
    int i = blockIdx.x * blockDim.x + threadIdx.x;
    if (i < n4) dst[i] = src[i];
}

__global__ void scatter_k(const float4* __restrict__ x4, const int* __restrict__ ei,
                          float* __restrict__ hp, int E) {
    int t = blockIdx.x * blockDim.x + threadIdx.x;
    int e = t >> 5;
    if (e >= E) return;
    int lane = t & 31;
    int src = ei[e];
    int dst = ei[E + e];
    float4 v = x4[(size_t)src * 32 + lane];
    float* p = hp + (size_t)dst * DIM + lane * 4;
    unsafeAtomicAdd(p + 0, v.x);
    unsafeAtomicAdd(p + 1, v.y);
    unsafeAtomicAdd(p + 2, v.z);
    unsafeAtomicAdd(p + 3, v.w);
}

__launch_bounds__(256)
__global__ void mlp_k(float* __restrict__ io,
                      const float* __restrict__ W1, const float* __restrict__ b1,
                      const float* __restrict__ W2, const float* __restrict__ b2,
                      int N) {
    __shared__ float Wl[DIM * DIM];
    __shared__ float As[32][DIM];
    const int tid = threadIdx.x;
    const int r0 = blockIdx.x * 32;
    const int tc = tid & 31;
    const int tr = tid >> 5;
    {
        const float4* w4 = (const float4*)W1;
        float4* wl4 = (float4*)Wl;
        #pragma unroll
        for (int i = 0; i < 16; ++i) wl4[tid + i * 256] = w4[tid + i * 256];
    }
    {
        const float4* io4 = (const float4*)io;
        float4* as4 = (float4*)As;
        #pragma unroll
        for (int i = 0; i < 4; ++i) {
            int p = tid + i * 256;
            int row = p >> 5;
            float4 v = make_float4(0.f, 0.f, 0.f, 0.f);
            if (r0 + row < N) v = io4[(size_t)(r0 + row) * 32 + (p & 31)];
            as4[p] = v;
        }
    }
    __syncthreads();
    float acc[4][4];
    #pragma unroll
    for (int i = 0; i < 4; ++i)
        #pragma unroll
        for (int j = 0; j < 4; ++j) acc[i][j] = 0.f;
    for (int kc = 0; kc < 32; ++kc) {
        float4 a[4], w[4];
        #pragma unroll
        for (int i = 0; i < 4; ++i) a[i] = *(const float4*)&As[tr * 4 + i][kc * 4];
        #pragma unroll
        for (int kk = 0; kk < 4; ++kk) w[kk] = *(const float4*)&Wl[(kc * 4 + kk) * DIM + tc * 4];
        float af[4][4];
        #pragma unroll
        for (int i = 0; i < 4; ++i) {
            af[i][0] = a[i].x; af[i][1] = a[i].y; af[i][2] = a[i].z; af[i][3] = a[i].w;
        }
        #pragma unroll
        for (int kk = 0; kk < 4; ++kk) {
            float wv[4] = {w[kk].x, w[kk].y, w[kk].z, w[kk].w};
            #pragma unroll
            for (int i = 0; i < 4; ++i)
                #pragma unroll
                for (int j = 0; j < 4; ++j)
                    acc[i][j] = fmaf(af[i][kk], wv[j], acc[i][j]);
        }
    }
    float4 bv1 = ((const float4*)b1)[tc];
    float h[4][4];
    #pragma unroll
    for (int i = 0; i < 4; ++i) {
        h[i][0] = fmaxf(acc[i][0] + bv1.x, 0.f);
        h[i][1] = fmaxf(acc[i][1] + bv1.y, 0.f);
        h[i][2] = fmaxf(acc[i][2] + bv1.z, 0.f);
        h[i][3] = fmaxf(acc[i][3] + bv1.w, 0.f);
    }
    __syncthreads();
    {
        const float4* w4 = (const float4*)W2;
        float4* wl4 = (float4*)Wl;
        #pragma unroll
        for (int i = 0; i < 16; ++i) wl4[tid + i * 256] = w4[tid + i * 256];
    }
    #pragma unroll
    for (int i = 0; i < 4; ++i)
        *(float4*)&As[tr * 4 + i][tc * 4] = make_float4(h[i][0], h[i][1], h[i][2], h[i][3]);
    __syncthreads();
    #pragma unroll
    for (int i = 0; i < 4; ++i)
        #pragma unroll
        for (int j = 0; j < 4; ++j) acc[i][j] = 0.f;
    for (int kc = 0; kc < 32; ++kc) {
        float4 a[4], w[4];
        #pragma unroll
        for (int i = 0; i < 4; ++i) a[i] = *(const float4*)&As[tr * 4 + i][kc * 4];
        #pragma unroll
        for (int kk = 0; kk < 4; ++kk) w[kk] = *(const float4*)&Wl[(kc * 4 + kk) * DIM + tc * 4];
        float af[4][4];
        #pragma unroll
        for (int i = 0; i < 4; ++i) {
            af[i][0] = a[i].x; af[i][1] = a[i].y; af[i][2] = a[i].z; af[i][3] = a[i].w;
        }
        #pragma unroll
        for (int kk = 0; kk < 4; ++kk) {
            float wv[4] = {w[kk].x, w[kk].y, w[kk].z, w[kk].w};
            #pragma unroll
            for (int i = 0; i < 4; ++i)
                #pragma unroll
                for (int j = 0; j < 4; ++j)
                    acc[i][j] = fmaf(af[i][kk], wv[j], acc[i][j]);
        }
    }
    float4 bv2 = ((const float4*)b2)[tc];
    float4* io4 = (float4*)io;
    #pragma unroll
    for (int ri = 0; ri < 4; ++ri) {
        int row = r0 + tr * 4 + ri;
        if (row < N) {
            float4 o = make_float4(acc[ri][0] + bv2.x, acc[ri][1] + bv2.y,
                                   acc[ri][2] + bv2.z, acc[ri][3] + bv2.w);
            io4[(size_t)row * 32 + tc] = o;
        }
    }
}

extern "C" void kernel_launch(void* const* d_in, const int* in_sizes, int n_in,
                              void* d_out, int out_size, void* d_ws, size_t ws_size,
                              hipStream_t stream) {
    const float* x  = (const float*)d_in[0];
    const int*   ei = (const int*)d_in[1];
    const float* W1 = (const float*)d_in[2];
    const float* b1 = (const float*)d_in[3];
    const float* W2 = (const float*)d_in[4];
    const float* b2 = (const float*)d_in[5];
    float* out = (float*)d_out;

    // primary ws layout: xb[12.8MB] | hpb[12.8MB] | head[50000] | nextsrc[640000 int2] | w1t | w2t
    const size_t xb_bytes = (size_t)NNODES * DIM * 2;       // 12,800,000
    const size_t hp_bytes = (size_t)NNODES * DIM * 2;       // 12,800,000
    const size_t head_bytes = (size_t)NNODES * sizeof(int); // 200,000
    const size_t ns_bytes = (size_t)NEDGES * sizeof(int2);  // 5,120,000
    const size_t wt_bytes = (size_t)DIM * DIM * 2;          // 32,768
    const size_t need_full = xb_bytes + hp_bytes + head_bytes + ns_bytes + 2 * wt_bytes;

    const size_t csr_ints = (size_t)(NNODES * 2 + (NNODES + 1) + NEDGES + 128);
    const size_t need_csr = csr_ints * sizeof(int);

    if (ws_size >= need_full) {
        char* p = (char*)d_ws;
        uint4* xb4  = (uint4*)p;                 p += xb_bytes;
        uint4* hpb4 = (uint4*)p;                 p += hp_bytes;
        int*   head = (int*)p;                   p += head_bytes;
        int2*  nextsrc = (int2*)p;               p += ns_bytes;
        u16*   w1t  = (u16*)p;
        u16*   w2t  = w1t + DIM * DIM;

        prep_k<<<CVT_BLKS + CVTW_BLKS + HEAD_BLKS, 256, 0, stream>>>(
            (const float4*)x, xb4, W1, W2, w1t, head);
        fill_ll_k<<<(NEDGES + 255) / 256, 256, 0, stream>>>(ei, head, nextsrc, NEDGES);
        gather_ll_k<<<(NNODES * 16 + 255) / 256, 256, 0, stream>>>(
            (const float4*)x, xb4, head, nextsrc, hpb4);
        mlp_mfma_k<<<(NNODES + 63) / 64, 256, 0, stream>>>(
            (const u16*)hpb4, out, w1t, b1, w2t, b2);
    } else if (ws_size >= need_csr) {
        int* deg = (int*)d_ws;
        int* cur = deg + NNODES;
        int* off = cur + NNODES;
        int* srclist = off + NNODES + 1;
        int* bsum = srclist + NEDGES;
        zero_k<<<(NNODES + 255) / 256, 256, 0, stream>>>(deg, NNODES);
        hist_k<<<(NEDGES + 255) / 256, 256, 0, stream>>>(ei, deg, NEDGES);
        scanA_k<<<SCAN_BLK, 256, 0, stream>>>(deg, bsum);
        scanC_k<<<SCAN_BLK, 256, 0, stream>>>(deg, bsum, off, cur);
        fill_k<<<(NEDGES + 255) / 256, 256, 0, stream>>>(ei, cur, srclist, NEDGES);
        gather_k<<<(NNODES * 32 + 255) / 256, 256, 0, stream>>>(
            (const float4*)x, off, srclist, (float4*)out);
        mlp_k<<<(NNODES + 31) / 32, 256, 0, stream>>>(out, W1, b1, W2, b2, NNODES);
    } else {
        int n4 = NNODES * DIM / 4;
        copy_k<<<(n4 + 255) / 256, 256, 0, stream>>>((const float4*)x, (float4*)out, n4);
        scatter_k<<<(NEDGES * 32 + 255) / 256, 256, 0, stream>>>((const float4*)x, ei, out, NEDGES);
        mlp_k<<<(NNODES + 31) / 32, 256, 0, stream>>>(out, W1, b1, W2, b2, NNODES);
    }
}